// Round 4
// baseline (1542.315 us; speedup 1.0000x reference)
//
#include <hip/hip_runtime.h>
#include <hip/hip_bf16.h>
#include <cstdint>

// ---------------------------------------------------------------------------
// RNN_CRF: BiLSTM(B=32,T=256,E=256,H=512) -> linear(K=32) -> CRF viterbi
// Persistent flag-synced LSTM. This rev: coalesced wave0 publish (1 wide
// sc0sc1 store instead of 512 short stores), per-step h slots (parity buffer
// merged with history), x-projection MFMAs overlapped with the flag wait.
// ---------------------------------------------------------------------------

typedef __attribute__((ext_vector_type(8)))  short          s8v;
typedef __attribute__((ext_vector_type(8)))  __bf16         bf8v;
typedef __attribute__((ext_vector_type(16))) float          f32x16;
typedef __attribute__((ext_vector_type(4)))  float          f32x4v;
typedef __attribute__((ext_vector_type(4)))  unsigned int   u32x4;
typedef __attribute__((ext_vector_type(8)))  unsigned short u16x8;
typedef __attribute__((ext_vector_type(4)))  unsigned short u16x4;

// ---- mfma shim: gfx950 builtin may take v8bf16 or v8i16 -------------------
template <typename V>
static __device__ inline auto mfma_try(V a, V b, f32x16 c, int)
    -> decltype(__builtin_amdgcn_mfma_f32_32x32x16_bf16(a, b, c, 0, 0, 0)) {
  return __builtin_amdgcn_mfma_f32_32x32x16_bf16(a, b, c, 0, 0, 0);
}
template <typename V>
static __device__ inline f32x16 mfma_try(V a, V b, f32x16 c, long) {
  return __builtin_amdgcn_mfma_f32_32x32x16_bf16(
      __builtin_bit_cast(bf8v, a), __builtin_bit_cast(bf8v, b), c, 0, 0, 0);
}
static __device__ inline f32x16 mfma32(u16x8 a, u16x8 b, f32x16 c) {
  return mfma_try(__builtin_bit_cast(s8v, a), __builtin_bit_cast(s8v, b), c, 0);
}

// ---- bf16 split helpers ---------------------------------------------------
static __device__ inline unsigned short bf_trunc(float x) {
  return (unsigned short)(__builtin_bit_cast(unsigned int, x) >> 16);
}
static __device__ inline float bf_up(unsigned short h) {
  return __builtin_bit_cast(float, ((unsigned int)h) << 16);
}
static __device__ inline void split2(float x, unsigned short& hi, unsigned short& lo) {
  hi = bf_trunc(x);
  lo = bf_trunc(x - bf_up(hi));
}
static __device__ inline float sigmoidf_(float x) { return 1.0f / (1.0f + __expf(-x)); }
static __device__ inline float tanhf_(float x) {
  float ax = fabsf(x);
  float e  = __expf(-2.0f * ax);
  float t  = (1.0f - e) / (1.0f + e);
  return x < 0.0f ? -t : t;
}

// ---- raw memory ops (untracked by compiler; manual waitcnt discipline) ----
static __device__ inline u32x4 ld16(const void* p) {           // cached
  u32x4 r;
  asm volatile("global_load_dwordx4 %0, %1, off" : "=v"(r) : "v"(p) : "memory");
  return r;
}
static __device__ inline u32x4 ld_cohere16(const void* p) {    // LLC-coherent
  u32x4 r;
  asm volatile("global_load_dwordx4 %0, %1, off sc0 sc1" : "=v"(r) : "v"(p) : "memory");
  return r;
}
static __device__ inline void st_cohere16(void* p, u32x4 v) {  // wide write-through
  asm volatile("global_store_dwordx4 %0, %1, off sc0 sc1" :: "v"(p), "v"(v) : "memory");
}
static __device__ inline void st_cohere4(void* p, int v) {
  asm volatile("global_store_dword %0, %1, off sc0 sc1" :: "v"(p), "v"(v) : "memory");
}
#define WAITVM(N)                                              \
  do {                                                         \
    asm volatile("s_waitcnt vmcnt(" #N ")" ::: "memory");      \
    __builtin_amdgcn_sched_barrier(0);                         \
  } while (0)

// ===========================================================================
// K1: embedding gather -> x split to bf16 hi/lo. row = t*32+b, 256 elems.
// ===========================================================================
__global__ void k_embed(const int* __restrict__ sent, const float* __restrict__ emb,
                        unsigned short* __restrict__ xhi, unsigned short* __restrict__ xlo) {
  int row  = blockIdx.x * 4 + (threadIdx.x >> 6);
  int lane = threadIdx.x & 63;
  int t = row >> 5, b = row & 31;
  int tok = sent[b * 256 + t];
  const f32x4v v = *(const f32x4v*)(emb + (long)tok * 256 + lane * 4);
  u16x4 h4, l4;
#pragma unroll
  for (int i = 0; i < 4; ++i) {
    unsigned short h, l;
    split2(v[i], h, l);
    h4[i] = h; l4[i] = l;
  }
  *(u16x4*)(xhi + (long)row * 256 + lane * 4) = h4;
  *(u16x4*)(xlo + (long)row * 256 + lane * 4) = l4;
}

// ===========================================================================
// K3: persistent bidirectional LSTM. 128 blocks: dir=blk>>6, b64=blk&63.
// h exchange via per-step slots: hist[dir][slot 0..256][b64][512 shorts]
// (hi 256 | lo 256). Slot s = h-state before consuming step-s input.
// Publish: gates -> LDS stage -> wave0 one dwordx4 sc0sc1 store per lane ->
// wave0 vmcnt(0) -> barrier -> tid0 flag. x-proj MFMAs run before the spin.
// ===========================================================================
__global__ __launch_bounds__(256, 1) void k_lstm(
    const float* __restrict__ Whh_f, const float* __restrict__ Whh_b,
    const float* __restrict__ Wih_f, const float* __restrict__ Wih_b,
    const float* __restrict__ b_f,   const float* __restrict__ b_b,
    const float* __restrict__ h0,    const float* __restrict__ c0,
    const unsigned short* __restrict__ xhi, const unsigned short* __restrict__ xlo,
    unsigned short* __restrict__ hist, int* __restrict__ flags) {
  const int tid = threadIdx.x, lane = tid & 63, w = tid >> 6;
  const int blk = blockIdx.x, dir = blk >> 6, b64 = blk & 63;
  const float* Whh  = dir ? Whh_b : Whh_f;
  const float* Wih  = dir ? Wih_b : Wih_f;
  const float* bias = dir ? b_b   : b_f;

  __shared__ float zp[4][32][33];
  __shared__ __align__(16) unsigned short hstage[512];  // hi 256 | lo 256

  const int n  = lane & 31;   // B-frag col == row-list index
  const int kh = lane >> 5;   // k half within 16-wide K step
  const int wrow = ((n >> 3) << 9) + (b64 << 3) + (n & 7);  // W row (gate*512+idx)

  // ---- preload recurrent B-frags (K=512, wave w covers [w*128, w*128+128))
  u16x8 wbh[8], wbl[8];
#pragma unroll
  for (int k8 = 0; k8 < 8; ++k8) {
    const float* src = Whh + (long)wrow * 512 + (w << 7) + (k8 << 4) + (kh << 3);
    f32x4v a = *(const f32x4v*)src, b2 = *(const f32x4v*)(src + 4);
    u16x8 hh, ll;
#pragma unroll
    for (int i = 0; i < 8; ++i) {
      float v = (i < 4) ? a[i] : b2[i - 4];
      unsigned short x1, x2; split2(v, x1, x2);
      hh[i] = x1; ll[i] = x2;
    }
    wbh[k8] = hh; wbl[k8] = ll;
  }
  // ---- preload input-proj B-frags (K=256, wave w covers [w*64, w*64+64))
  u16x8 wih_h[4], wih_l[4];
#pragma unroll
  for (int k4 = 0; k4 < 4; ++k4) {
    const float* src = Wih + (long)wrow * 256 + (w << 6) + (k4 << 4) + (kh << 3);
    f32x4v a = *(const f32x4v*)src, b2 = *(const f32x4v*)(src + 4);
    u16x8 hh, ll;
#pragma unroll
    for (int i = 0; i < 8; ++i) {
      float v = (i < 4) ? a[i] : b2[i - 4];
      unsigned short x1, x2; split2(v, x1, x2);
      hh[i] = x1; ll[i] = x2;
    }
    wih_h[k4] = hh; wih_l[k4] = ll;
  }

  // ---- gate-thread state
  const int gb = tid & 31;          // batch
  const int gi = tid >> 5;          // local h index 0..7
  const int gidx = (b64 << 3) + gi; // global h index
  float c = c0[(dir * 32 + gb) * 512 + gidx];
  float bias4[4];
#pragma unroll
  for (int g = 0; g < 4; ++g) bias4[g] = bias[(g << 9) + gidx];

  // ---- publish h_0 into slot 0
  {
    float hv = h0[(dir * 32 + gb) * 512 + gidx];
    unsigned short hh, ll; split2(hv, hh, ll);
    hstage[gb * 8 + gi] = hh;
    hstage[256 + gb * 8 + gi] = ll;
  }
  __syncthreads();
  if (w == 0) {
    const u32x4* hs = (const u32x4*)hstage;
    u32x4 v = hs[lane];
    char* dst = (char*)hist + (((long)dir * 257 + 0) * 64 + b64) * 1024 + lane * 16;
    st_cohere16(dst, v);
    WAITVM(0);
  }
  __syncthreads();
  if (tid == 0) st_cohere4(flags + dir * 64 + b64, 1);

  const int m = lane & 31;  // A-frag row == batch

  // ---- prefetch x for step 0
  u32x4 xah_[4], xal_[4];
  {
    const int t0 = dir ? 255 : 0;
#pragma unroll
    for (int k4 = 0; k4 < 4; ++k4) {
      long ro = (long)(t0 * 32 + m) * 256 + (w << 6) + (k4 << 4) + (kh << 3);
      xah_[k4] = ld16(xhi + ro);
      xal_[k4] = ld16(xlo + ro);
    }
  }

  for (int step = 0; step < 256; ++step) {
    // (1) x ready (prefetched last iteration); also drains wave0's flag store
    WAITVM(0);
    f32x16 acc0 = (f32x16)0.0f, acc1 = (f32x16)0.0f;
#pragma unroll
    for (int k4 = 0; k4 < 4; ++k4) {
      u16x8 xa = __builtin_bit_cast(u16x8, xah_[k4]);
      u16x8 xl = __builtin_bit_cast(u16x8, xal_[k4]);
      if (k4 & 1) {
        acc1 = mfma32(xa, wih_h[k4], acc1);
        acc0 = mfma32(xa, wih_l[k4], acc0);
        acc1 = mfma32(xl, wih_h[k4], acc1);
      } else {
        acc0 = mfma32(xa, wih_h[k4], acc0);
        acc1 = mfma32(xa, wih_l[k4], acc1);
        acc0 = mfma32(xl, wih_h[k4], acc0);
      }
    }
    __builtin_amdgcn_sched_barrier(0);  // keep x-proj above the spin

    // (2) wait for all 64 producer blocks of this direction
    {
      const int* fl = flags + dir * 64;
      const int tgt = step + 1;
      while (true) {
        int fv = __hip_atomic_load(fl + lane, __ATOMIC_RELAXED, __HIP_MEMORY_SCOPE_AGENT);
        if (__all(fv >= tgt)) break;
      }
    }

    // (3) h A-frag loads from slot `step`
    const unsigned short* hb = hist + (((long)dir * 257 + step) * 64) * 512;
    u32x4 ah_[8], al_[8];
#pragma unroll
    for (int k8 = 0; k8 < 8; ++k8) {
      int bs = (w << 4) + (k8 << 1) + kh;
      ah_[k8] = ld_cohere16(hb + bs * 512 + m * 8);
      al_[k8] = ld_cohere16(hb + bs * 512 + 256 + m * 8);
    }

    // (4) recurrent MFMAs, staged on vmcnt
    WAITVM(8);
#pragma unroll
    for (int k8 = 0; k8 < 4; ++k8) {
      u16x8 ah = __builtin_bit_cast(u16x8, ah_[k8]);
      u16x8 al = __builtin_bit_cast(u16x8, al_[k8]);
      if (k8 & 1) {
        acc1 = mfma32(ah, wbh[k8], acc1);
        acc0 = mfma32(ah, wbl[k8], acc0);
        acc1 = mfma32(al, wbh[k8], acc1);
      } else {
        acc0 = mfma32(ah, wbh[k8], acc0);
        acc1 = mfma32(ah, wbl[k8], acc1);
        acc0 = mfma32(al, wbh[k8], acc0);
      }
    }
    WAITVM(0);
#pragma unroll
    for (int k8 = 4; k8 < 8; ++k8) {
      u16x8 ah = __builtin_bit_cast(u16x8, ah_[k8]);
      u16x8 al = __builtin_bit_cast(u16x8, al_[k8]);
      if (k8 & 1) {
        acc1 = mfma32(ah, wbh[k8], acc1);
        acc0 = mfma32(ah, wbl[k8], acc0);
        acc1 = mfma32(al, wbh[k8], acc1);
      } else {
        acc0 = mfma32(ah, wbh[k8], acc0);
        acc1 = mfma32(ah, wbl[k8], acc1);
        acc0 = mfma32(al, wbh[k8], acc0);
      }
    }

    // (5) partial z to LDS: C row = (reg&3)+8*(reg>>2)+4*kh (batch), col = n
#pragma unroll
    for (int r = 0; r < 16; ++r) {
      int mr = (r & 3) + ((r >> 2) << 3) + (kh << 2);
      zp[w][mr][n] = acc0[r] + acc1[r];
    }
    __syncthreads();

    // (6) gate math
    float z[4];
#pragma unroll
    for (int g = 0; g < 4; ++g)
      z[g] = zp[0][gb][g * 8 + gi] + zp[1][gb][g * 8 + gi] +
             zp[2][gb][g * 8 + gi] + zp[3][gb][g * 8 + gi] + bias4[g];
    float ig = sigmoidf_(z[0]);
    float fg = sigmoidf_(z[1]);
    float gg = tanhf_(z[2]);
    float og = sigmoidf_(z[3]);
    c = fg * c + ig * gg;
    float nh = og * tanhf_(c);
    unsigned short hh, ll; split2(nh, hh, ll);

    // (7) prefetch x for next step (completes during publish + next spin)
    if (step < 255) {
      const int tn = dir ? (254 - step) : (step + 1);
#pragma unroll
      for (int k4 = 0; k4 < 4; ++k4) {
        long ro = (long)(tn * 32 + m) * 256 + (w << 6) + (k4 << 4) + (kh << 3);
        xah_[k4] = ld16(xhi + ro);
        xal_[k4] = ld16(xlo + ro);
      }
    }

    // (8) publish h into slot step+1: LDS stage -> wave0 wide coalesced store
    hstage[gb * 8 + gi] = hh;
    hstage[256 + gb * 8 + gi] = ll;
    __syncthreads();
    if (w == 0) {
      const u32x4* hs = (const u32x4*)hstage;
      u32x4 v = hs[lane];
      char* dst = (char*)hist + (((long)dir * 257 + step + 1) * 64 + b64) * 1024 + lane * 16;
      st_cohere16(dst, v);
      WAITVM(0);  // wave0-only drain: one wide store (+its x prefetch)
    }
    __syncthreads();
    if (tid == 0) st_cohere4(flags + dir * 64 + b64, step + 2);
  }
}

// ===========================================================================
// K4: feats[b,t,k] = concat(hf,hb) @ Wout^T + bout. One block per t.
// h_f[t] = hist[0][t+1], h_b[t] = hist[1][256-t].
// ===========================================================================
__global__ __launch_bounds__(256, 1) void k_feats(
    const unsigned short* __restrict__ hist,
    const float* __restrict__ Wout, const float* __restrict__ bout,
    float* __restrict__ feats) {
  const int tid = threadIdx.x, lane = tid & 63, w = tid >> 6;
  const int t = blockIdx.x;
  __shared__ float zp[4][32][33];
  const int n = lane & 31, kh = lane >> 5;
  const int dirw = w >> 1, koff = (w & 1) * 256;

  u16x8 bh[16], bl[16];
#pragma unroll
  for (int k = 0; k < 16; ++k) {
    const float* src = Wout + (long)n * 1024 + dirw * 512 + koff + (k << 4) + (kh << 3);
    f32x4v a = *(const f32x4v*)src, b2 = *(const f32x4v*)(src + 4);
    u16x8 hh, ll;
#pragma unroll
    for (int i = 0; i < 8; ++i) {
      float v = (i < 4) ? a[i] : b2[i - 4];
      unsigned short x1, x2; split2(v, x1, x2);
      hh[i] = x1; ll[i] = x2;
    }
    bh[k] = hh; bl[k] = ll;
  }

  const int m = lane & 31;  // batch
  const int slot = dirw ? (256 - t) : (t + 1);
  const unsigned short* base = hist + (((long)dirw * 257 + slot) * 64) * 512;
  f32x16 acc = (f32x16)0.0f;
#pragma unroll
  for (int k = 0; k < 16; ++k) {
    int ksrc = koff + (k << 4) + (kh << 3);
    int bs = ksrc >> 3;
    u16x8 ah = *(const u16x8*)(base + bs * 512 + m * 8);
    u16x8 al = *(const u16x8*)(base + bs * 512 + 256 + m * 8);
    acc = mfma32(ah, bh[k], acc);
    acc = mfma32(ah, bl[k], acc);
    acc = mfma32(al, bh[k], acc);
  }
#pragma unroll
  for (int r = 0; r < 16; ++r) {
    int mr = (r & 3) + ((r >> 2) << 3) + (kh << 2);
    zp[w][mr][n] = acc[r];
  }
  __syncthreads();

  const int k = tid & 31, mb = tid >> 5;
#pragma unroll
  for (int q = 0; q < 4; ++q) {
    int mm = mb * 4 + q;  // batch
    float v = zp[0][mm][k] + zp[1][mm][k] + zp[2][mm][k] + zp[3][mm][k] + bout[k];
    feats[((long)mm * 256 + t) * 32 + k] = v;
  }
}

// ===========================================================================
// K5: Viterbi. One wave per batch, barrier-free scan.
// ===========================================================================
__global__ __launch_bounds__(64, 1) void k_viterbi(const float* __restrict__ feats,
                                                   const float* __restrict__ trans,
                                                   float* __restrict__ out) {
  const int b = blockIdx.x, lane = threadIdx.x;
  __shared__ __align__(16) float fsh[256][32];
  __shared__ unsigned char bp[256][32];

  const float* fb = feats + (long)b * 8192;
#pragma unroll 4
  for (int i = lane; i < 2048; i += 64)
    ((f32x4v*)&fsh[0][0])[i] = ((const f32x4v*)fb)[i];

  float tr_[32];
  float vl = 0.0f;
  if (lane < 32) {
#pragma unroll
    for (int p = 0; p < 32; ++p) tr_[p] = trans[lane * 32 + p];
    vl = (lane == 30) ? 0.0f : -10000.0f;
  }
  __syncthreads();

  if (lane < 32) {
    for (int t = 0; t < 256; ++t) {
      float best = -3.0e38f; int arg = 0;
#pragma unroll
      for (int p = 0; p < 32; ++p) {
        float vp = __shfl(vl, p, 32);
        float sc = vp + tr_[p];
        if (sc > best) { best = sc; arg = p; }  // strict > keeps FIRST max
      }
      vl = best + fsh[t][lane];
      bp[t][lane] = (unsigned char)arg;
    }
    float tv = vl + trans[31 * 32 + lane];
    int ta = lane;
#pragma unroll
    for (int d = 16; d; d >>= 1) {
      float ov = __shfl_xor(tv, d, 32);
      int   oa = __shfl_xor(ta, d, 32);
      if (ov > tv || (ov == tv && oa < ta)) { tv = ov; ta = oa; }
    }
    if (lane == 0) {
      out[b] = tv;
      int tag = ta;
      for (int t = 255; t >= 0; --t) {
        out[32 + (long)b * 256 + t] = (float)tag;
        tag = bp[t][tag];
      }
    }
  }
}

// ===========================================================================
extern "C" void kernel_launch(void* const* d_in, const int* in_sizes, int n_in,
                              void* d_out, int out_size, void* d_ws, size_t ws_size,
                              hipStream_t stream) {
  (void)in_sizes; (void)n_in; (void)out_size; (void)ws_size;
  const int*   sent  = (const int*)d_in[0];
  const float* emb   = (const float*)d_in[1];
  const float* Wih_f = (const float*)d_in[2];
  const float* Whh_f = (const float*)d_in[3];
  const float* b_f   = (const float*)d_in[4];
  const float* Wih_b = (const float*)d_in[5];
  const float* Whh_b = (const float*)d_in[6];
  const float* b_b   = (const float*)d_in[7];
  const float* Wout  = (const float*)d_in[8];
  const float* bout  = (const float*)d_in[9];
  const float* trans = (const float*)d_in[10];
  const float* h0    = (const float*)d_in[11];
  const float* c0    = (const float*)d_in[12];
  float* out = (float*)d_out;

  char* ws = (char*)d_ws;
  unsigned short* xhi  = (unsigned short*)(ws + 0);              // 4 MB
  unsigned short* xlo  = (unsigned short*)(ws + (4ull << 20));   // 4 MB
  unsigned short* hist = (unsigned short*)(ws + (8ull << 20));   // 2*257*64KB ~= 32.1 MB
  float*          fts  = (float*)(ws + (42ull << 20));           // 1 MB
  int*            flg  = (int*)(ws + (44ull << 20));             // 512 B

  hipMemsetAsync(flg, 0, 128 * sizeof(int), stream);
  k_embed<<<2048, 256, 0, stream>>>(sent, emb, xhi, xlo);
  k_lstm<<<128, 256, 0, stream>>>(Whh_f, Whh_b, Wih_f, Wih_b, b_f, b_b, h0, c0,
                                  xhi, xlo, hist, flg);
  k_feats<<<256, 256, 0, stream>>>(hist, Wout, bout, fts);
  k_viterbi<<<32, 64, 0, stream>>>(fts, trans, out);
}